// Round 5
// baseline (232.455 us; speedup 1.0000x reference)
//
#include <hip/hip_runtime.h>
#include <math.h>

#define MB 8
#define NH 8
#define HID 128
#define SEQ 1024
#define DIN 1024
#define HBN 64  // NH*MB

typedef __bf16 bf16x8 __attribute__((ext_vector_type(8)));
typedef __attribute__((ext_vector_type(4))) float f32x4;
typedef __attribute__((ext_vector_type(8))) unsigned short u16x8;
typedef __attribute__((ext_vector_type(4))) unsigned short u16x4;

__device__ inline unsigned short f2bf(float f) {  // RNE f32->bf16
  unsigned int u = __builtin_bit_cast(unsigned int, f);
  u = (u + 0x7FFFu + ((u >> 16) & 1u)) >> 16;
  return (unsigned short)u;
}

// exp(tanh(x)) via hardware exp2/rcp. Saturates correctly for |x| large.
__device__ inline float fast_expt(float x) {
  float e2 = __builtin_amdgcn_exp2f(x * 2.885390082f);        // e^(2x)
  float t = fmaf(-2.f, __builtin_amdgcn_rcpf(e2 + 1.f), 1.f); // tanh(x)
  return __builtin_amdgcn_exp2f(t * 1.442695041f);            // e^tanh
}

__device__ inline void gload_lds16(const void* g, void* l) {
  __builtin_amdgcn_global_load_lds(
      (const __attribute__((address_space(1))) void*)g,
      (__attribute__((address_space(3))) void*)l, 16, 0, 0);
}

// ---------------- merged prep kernel ----------------
// z=0: WkT = bf16(Wk^T); z=1: WpT = bf16(Wp^T); z=2: wq_fold rows
__global__ __launch_bounds__(256) void prep_kernel(
    const float* __restrict__ Wk, const float* __restrict__ Wp,
    const float* __restrict__ Wq, const float* __restrict__ w,
    unsigned short* __restrict__ WkT, unsigned short* __restrict__ WpT,
    float* __restrict__ u) {
  const int z = blockIdx.z;
  const int tid = threadIdx.x;
  if (z < 2) {
    __shared__ unsigned short tile[64][65];
    const float* W = (z == 0) ? Wk : Wp;
    unsigned short* WT = (z == 0) ? WkT : WpT;
    const int bx = blockIdx.x * 64;  // k block
    const int by = blockIdx.y * 64;  // n block
    const int r = tid >> 4;
    const int c4 = tid & 15;
#pragma unroll
    for (int i = 0; i < 4; i++) {
      const int rr = r + i * 16;
      float4 v = *reinterpret_cast<const float4*>(W + (size_t)(bx + rr) * DIN + by + c4 * 4);
      tile[c4 * 4 + 0][rr] = f2bf(v.x);
      tile[c4 * 4 + 1][rr] = f2bf(v.y);
      tile[c4 * 4 + 2][rr] = f2bf(v.z);
      tile[c4 * 4 + 3][rr] = f2bf(v.w);
    }
    __syncthreads();
#pragma unroll
    for (int i = 0; i < 4; i++) {
      const int rr = r + i * 16;
      u16x4 o = {tile[rr][c4 * 4 + 0], tile[rr][c4 * 4 + 1],
                 tile[rr][c4 * 4 + 2], tile[rr][c4 * 4 + 3]};
      *reinterpret_cast<u16x4*>(WT + (size_t)(by + rr) * DIN + bx + c4 * 4) = o;
    }
  } else {
    // u[row][h] = sum_d Wq[row][h*128+d]*w[128+d], rows 0..1023
    const int lane = tid & 63;
    const int wv = tid >> 6;
    const int bid = blockIdx.x + blockIdx.y * 16;  // 0..255
    const int row = bid * 4 + wv;
    const int h = lane >> 3, sub = lane & 7;
    const float* src = Wq + (size_t)row * DIN;
    float p = 0.f;
    const int col0 = h * HID + sub * 16;
#pragma unroll
    for (int i = 0; i < 16; i++) p = fmaf(src[col0 + i], w[HID + sub * 16 + i], p);
    p += __shfl_xor(p, 1);
    p += __shfl_xor(p, 2);
    p += __shfl_xor(p, 4);
    if (sub == 0) u[(size_t)row * 8 + h] = p;
  }
}

// qs[(h*MB+b)*SEQ + t] = q[b,t,:] . u[:,h] + (bq . w-seg fold)
__global__ __launch_bounds__(256) void qs_kernel(const float* __restrict__ q,
                                                 const float* __restrict__ u,
                                                 const float* __restrict__ bq,
                                                 const float* __restrict__ w,
                                                 float* __restrict__ qs) {
  __shared__ float ul[DIN * 9];
  __shared__ float cs[8];
  const int tid = threadIdx.x;
  for (int idx = tid; idx < DIN * 8; idx += 256)
    ul[(idx >> 3) * 9 + (idx & 7)] = u[idx];
  if (tid < 64) {  // bias fold: cs[h] = sum_d bq[h*128+d]*w[128+d]
    const int h = tid >> 3, sub = tid & 7;
    float p = 0.f;
#pragma unroll
    for (int i = 0; i < 16; i++)
      p = fmaf(bq[h * HID + sub * 16 + i], w[HID + sub * 16 + i], p);
    p += __shfl_xor(p, 1);
    p += __shfl_xor(p, 2);
    p += __shfl_xor(p, 4);
    if (sub == 0) cs[h] = p;
  }
  __syncthreads();
  const int lane = tid & 63, wv = tid >> 6;
  const int m = blockIdx.x * 4 + wv;  // (b,t) row, 0..8191
  const int b = m >> 10, t = m & 1023;
  float a0 = 0, a1 = 0, a2 = 0, a3 = 0, a4 = 0, a5 = 0, a6 = 0, a7 = 0;
  const float* qrow = q + (size_t)m * DIN;
#pragma unroll
  for (int i = 0; i < 16; i++) {
    const int din = lane + i * 64;
    const float v = qrow[din];
    const float* up = ul + din * 9;
    a0 = fmaf(v, up[0], a0); a1 = fmaf(v, up[1], a1);
    a2 = fmaf(v, up[2], a2); a3 = fmaf(v, up[3], a3);
    a4 = fmaf(v, up[4], a4); a5 = fmaf(v, up[5], a5);
    a6 = fmaf(v, up[6], a6); a7 = fmaf(v, up[7], a7);
  }
#pragma unroll
  for (int off = 1; off < 64; off <<= 1) {
    a0 += __shfl_xor(a0, off); a1 += __shfl_xor(a1, off);
    a2 += __shfl_xor(a2, off); a3 += __shfl_xor(a3, off);
    a4 += __shfl_xor(a4, off); a5 += __shfl_xor(a5, off);
    a6 += __shfl_xor(a6, off); a7 += __shfl_xor(a7, off);
  }
  if (lane == 0) {
    qs[((size_t)(0 * MB + b) << 10) + t] = a0 + cs[0];
    qs[((size_t)(1 * MB + b) << 10) + t] = a1 + cs[1];
    qs[((size_t)(2 * MB + b) << 10) + t] = a2 + cs[2];
    qs[((size_t)(3 * MB + b) << 10) + t] = a3 + cs[3];
    qs[((size_t)(4 * MB + b) << 10) + t] = a4 + cs[4];
    qs[((size_t)(5 * MB + b) << 10) + t] = a5 + cs[5];
    qs[((size_t)(6 * MB + b) << 10) + t] = a6 + cs[6];
    qs[((size_t)(7 * MB + b) << 10) + t] = a7 + cs[7];
  }
}

// ---------------- bf16 MFMA GEMM (128x128 tile, BK=32) ----------------
// MODE 0 (KPROJ): Af=k f32 (reg-staged->bf16), BT=WkT, +bias
//                 -> kxT[hb][d][t] bf16, ks f32
// MODE 2 (OUT):   A=att gathered bf16, BT=WpT, +bias -> out f32 (nt)
template <int MODE>
__global__ __launch_bounds__(256) void mfma_gemm(
    const unsigned short* __restrict__ A, const float* __restrict__ Af,
    const unsigned short* __restrict__ BT, const float* __restrict__ bias,
    const float* __restrict__ wseg, unsigned short* __restrict__ Cb,
    float* __restrict__ Cf, float* __restrict__ rowdot, int M, int N, int K) {
  __shared__ __align__(16) unsigned short Alds[128 * 32];
  __shared__ __align__(16) unsigned short Blds[128 * 32];

  const int tid = threadIdx.x;
  const int lane = tid & 63;
  const int wv = tid >> 6;
  const int g = lane >> 4;
  const int c = lane & 15;
  const int bm = blockIdx.y * 128;
  const int bn = blockIdx.x * 128;

  f32x4 acc[2][8];
#pragma unroll
  for (int m = 0; m < 2; m++)
#pragma unroll
    for (int n = 0; n < 8; n++) acc[m][n] = (f32x4){0.f, 0.f, 0.f, 0.f};

  for (int kt = 0; kt < K; kt += 32) {
#pragma unroll
    for (int i = 0; i < 2; i++) {
      const int cidx = i * 256 + tid;  // chunk of 8 bf16
      const int row = cidx >> 2;
      const int ko = (cidx & 3) << 3;
      if constexpr (MODE == 0) {
        // reg-stage f32 k -> bf16 LDS (fuses the cast pass)
        const float* src = Af + (size_t)(bm + row) * K + kt + ko;
        const float4 v0 = *reinterpret_cast<const float4*>(src);
        const float4 v1 = *reinterpret_cast<const float4*>(src + 4);
        u16x8 p;
        p[0] = f2bf(v0.x); p[1] = f2bf(v0.y); p[2] = f2bf(v0.z); p[3] = f2bf(v0.w);
        p[4] = f2bf(v1.x); p[5] = f2bf(v1.y); p[6] = f2bf(v1.z); p[7] = f2bf(v1.w);
        *reinterpret_cast<u16x8*>(Alds + cidx * 8) = p;
      } else {
        const int gr = bm + row;
        const int b = gr >> 10, t = gr & 1023;
        const int kk = kt + ko;
        const int h = kk >> 7, d = kk & 127;
        gload_lds16(A + (((size_t)(h * MB + b) * SEQ + t) << 7) + d,
                    Alds + cidx * 8);
      }
      gload_lds16(BT + (size_t)(bn + row) * K + kt + ko, Blds + cidx * 8);
    }
    __syncthreads();

    bf16x8 af[2], bfr[8];
#pragma unroll
    for (int m = 0; m < 2; m++)
      af[m] = *reinterpret_cast<const bf16x8*>(
          Alds + ((wv * 32 + m * 16 + c) * 32 + g * 8));
#pragma unroll
    for (int n = 0; n < 8; n++)
      bfr[n] = *reinterpret_cast<const bf16x8*>(Blds + ((n * 16 + c) * 32 + g * 8));
#pragma unroll
    for (int m = 0; m < 2; m++)
#pragma unroll
      for (int n = 0; n < 8; n++)
        acc[m][n] = __builtin_amdgcn_mfma_f32_16x16x32_bf16(af[m], bfr[n],
                                                            acc[m][n], 0, 0, 0);
    __syncthreads();
  }

  if constexpr (MODE == 0) {
    const int h = bn >> 7;           // tile spans exactly one head
    const int b = bm >> 10;          // tile spans one batch row-block
    const size_t hb = h * MB + b;
    const int tbase = (bm & (SEQ - 1)) + wv * 32;
    float wl[8], bl[8];
#pragma unroll
    for (int n = 0; n < 8; n++) {
      wl[n] = wseg[n * 16 + c];
      bl[n] = bias[bn + n * 16 + c];
    }
#pragma unroll
    for (int m = 0; m < 2; m++) {
      const int t0 = tbase + m * 16 + g * 4;
      float pr0 = 0, pr1 = 0, pr2 = 0, pr3 = 0;
#pragma unroll
      for (int n = 0; n < 8; n++) {
        f32x4 a4 = acc[m][n];
        const float v0 = a4[0] + bl[n], v1 = a4[1] + bl[n];
        const float v2 = a4[2] + bl[n], v3 = a4[3] + bl[n];
        pr0 = fmaf(v0, wl[n], pr0); pr1 = fmaf(v1, wl[n], pr1);
        pr2 = fmaf(v2, wl[n], pr2); pr3 = fmaf(v3, wl[n], pr3);
        u16x4 o = {f2bf(v0), f2bf(v1), f2bf(v2), f2bf(v3)};
        *reinterpret_cast<u16x4*>(Cb + (hb * HID + n * 16 + c) * SEQ + t0) = o;
      }
#pragma unroll
      for (int off = 1; off < 16; off <<= 1) {
        pr0 += __shfl_xor(pr0, off); pr1 += __shfl_xor(pr1, off);
        pr2 += __shfl_xor(pr2, off); pr3 += __shfl_xor(pr3, off);
      }
      if (c == 0) {
        float* rd = rowdot + hb * SEQ + t0;
        rd[0] = pr0; rd[1] = pr1; rd[2] = pr2; rd[3] = pr3;
      }
    }
  } else {
#pragma unroll
    for (int m = 0; m < 2; m++) {
      const int r0 = bm + wv * 32 + m * 16 + g * 4;
#pragma unroll
      for (int n = 0; n < 8; n++) {
        f32x4 a4 = acc[m][n];
        const float bb = bias[bn + n * 16 + c];
#pragma unroll
        for (int r = 0; r < 4; r++)
          __builtin_nontemporal_store(a4[r] + bb,
                                      Cf + (size_t)(r0 + r) * N + bn + n * 16 + c);
      }
    }
  }
}

// ---------------- fused score-gen + PV ----------------
__global__ __launch_bounds__(256) void pv_fused(
    const unsigned short* __restrict__ kxT,  // [hb][d][t] bf16
    const float* __restrict__ ks, const float* __restrict__ qs,
    float* __restrict__ score, unsigned short* __restrict__ att) {
  __shared__ __align__(16) unsigned short Alds[128 * 32];
  __shared__ __align__(16) unsigned short Blds[128 * 32];
  __shared__ __align__(16) float ksl[SEQ];
  __shared__ __align__(16) float qvl[128];
  __shared__ float invl[128];

  const int tid = threadIdx.x;
  const int hb = blockIdx.y;
  const int bm = blockIdx.x * 128;  // q offset within hb
  const int lane = tid & 63, wv = tid >> 6, g = lane >> 4, c = lane & 15;

  // load ks (full row) and the block's 128 qs values
  for (int i = tid; i < SEQ / 4; i += 256)
    *reinterpret_cast<float4*>(ksl + i * 4) =
        *reinterpret_cast<const float4*>(ks + ((size_t)hb << 10) + i * 4);
  if (tid < 32)
    *reinterpret_cast<float4*>(qvl + tid * 4) = *reinterpret_cast<const float4*>(
        qs + ((size_t)hb << 10) + bm + tid * 4);
  __syncthreads();

  // per-row softmax denominators (2 threads per row)
  {
    const int r = tid >> 1, h = tid & 1;
    const float qv = qvl[r];
    const float* kk = ksl + h * 512;
    float s0 = 0.f, s1 = 0.f;
    for (int i = 0; i < 512; i += 2) {
      s0 += fast_expt(qv + kk[i]);
      s1 += fast_expt(qv + kk[i + 1]);
    }
    float s = s0 + s1;
    s += __shfl_xor(s, 1);
    if (h == 0) invl[r] = __builtin_amdgcn_rcpf(s);
  }
  __syncthreads();

  f32x4 acc[2][8];
#pragma unroll
  for (int m = 0; m < 2; m++)
#pragma unroll
    for (int n = 0; n < 8; n++) acc[m][n] = (f32x4){0.f, 0.f, 0.f, 0.f};

  for (int kt = 0; kt < SEQ; kt += 32) {
// stage kxT slab (B operand)
#pragma unroll
    for (int i = 0; i < 2; i++) {
      const int cidx = i * 256 + tid;
      const int row = cidx >> 2;       // d
      const int ko = (cidx & 3) << 3;  // k offset
      gload_lds16(kxT + ((size_t)hb * HID + row) * SEQ + kt + ko, Blds + cidx * 8);
    }
// generate P slab: normalize, write f32 score (nt), stage bf16 to LDS
#pragma unroll
    for (int i = 0; i < 2; i++) {
      const int cidx = i * 256 + tid;
      const int row = cidx >> 2;       // q row in tile
      const int ko = (cidx & 3) << 3;
      const float qv = qvl[row];
      const float inv = invl[row];
      const float4 k0 = *reinterpret_cast<const float4*>(ksl + kt + ko);
      const float4 k1 = *reinterpret_cast<const float4*>(ksl + kt + ko + 4);
      const float p0 = fast_expt(qv + k0.x) * inv;
      const float p1 = fast_expt(qv + k0.y) * inv;
      const float p2 = fast_expt(qv + k0.z) * inv;
      const float p3 = fast_expt(qv + k0.w) * inv;
      const float p4 = fast_expt(qv + k1.x) * inv;
      const float p5 = fast_expt(qv + k1.y) * inv;
      const float p6 = fast_expt(qv + k1.z) * inv;
      const float p7 = fast_expt(qv + k1.w) * inv;
      float* sp = score + ((size_t)hb << 20) + ((size_t)(bm + row) << 10) + kt + ko;
      const f32x4 w0 = {p0, p1, p2, p3};
      const f32x4 w1 = {p4, p5, p6, p7};
      __builtin_nontemporal_store(w0, reinterpret_cast<f32x4*>(sp));
      __builtin_nontemporal_store(w1, reinterpret_cast<f32x4*>(sp + 4));
      bf16x8 pb;
      pb[0] = (__bf16)p0; pb[1] = (__bf16)p1; pb[2] = (__bf16)p2; pb[3] = (__bf16)p3;
      pb[4] = (__bf16)p4; pb[5] = (__bf16)p5; pb[6] = (__bf16)p6; pb[7] = (__bf16)p7;
      *reinterpret_cast<bf16x8*>(Alds + (size_t)cidx * 8) = pb;
    }
    __syncthreads();

    bf16x8 af[2], bfr[8];
#pragma unroll
    for (int m = 0; m < 2; m++)
      af[m] = *reinterpret_cast<const bf16x8*>(
          Alds + ((wv * 32 + m * 16 + c) * 32 + g * 8));
#pragma unroll
    for (int n = 0; n < 8; n++)
      bfr[n] = *reinterpret_cast<const bf16x8*>(Blds + ((n * 16 + c) * 32 + g * 8));
#pragma unroll
    for (int m = 0; m < 2; m++)
#pragma unroll
      for (int n = 0; n < 8; n++)
        acc[m][n] = __builtin_amdgcn_mfma_f32_16x16x32_bf16(af[m], bfr[n],
                                                            acc[m][n], 0, 0, 0);
    __syncthreads();
  }

// epilogue: att[hb][q][d] bf16
#pragma unroll
  for (int m = 0; m < 2; m++) {
    const int q0 = bm + wv * 32 + m * 16 + g * 4;
#pragma unroll
    for (int n = 0; n < 8; n++) {
      f32x4 a4 = acc[m][n];
#pragma unroll
      for (int r = 0; r < 4; r++)
        att[((size_t)hb * SEQ + q0 + r) * HID + n * 16 + c] = f2bf(a4[r]);
    }
  }
}

extern "C" void kernel_launch(void* const* d_in, const int* in_sizes, int n_in,
                              void* d_out, int out_size, void* d_ws,
                              size_t ws_size, hipStream_t stream) {
  const float* k = (const float*)d_in[0];
  const float* q = (const float*)d_in[1];
  const float* Wk = (const float*)d_in[2];
  const float* bk = (const float*)d_in[3];
  const float* Wq = (const float*)d_in[4];
  const float* bq = (const float*)d_in[5];
  const float* w = (const float*)d_in[6];
  const float* Wp = (const float*)d_in[7];
  const float* bp = (const float*)d_in[8];

  float* out_ptr = (float*)d_out;                       // (8,1024,1024) f32
  float* score_ptr = out_ptr + (size_t)MB * SEQ * DIN;  // (64,1024,1024) f32

  char* wsb = (char*)d_ws;
  unsigned short* WkT = (unsigned short*)(wsb);             // 2 MB
  unsigned short* WpT = (unsigned short*)(wsb + 2097152);   // 2 MB
  unsigned short* kxT = (unsigned short*)(wsb + 4194304);   // 16 MB [hb][d][t]
  unsigned short* att = (unsigned short*)(wsb + 20971520);  // 16 MB [hb][t][d]
  float* ks = (float*)(wsb + 37748736);                     // 256 KB
  float* qs = (float*)(wsb + 38010880);                     // 256 KB
  float* u = (float*)(wsb + 38273024);                      // 32 KB

  // prep: WkT, WpT transposes + Wq fold (z slices)
  prep_kernel<<<dim3(16, 16, 3), dim3(256), 0, stream>>>(Wk, Wp, Wq, w, WkT,
                                                         WpT, u);
  qs_kernel<<<dim3(2048), dim3(256), 0, stream>>>(q, u, bq, w, qs);
  // k-projection (f32 k reg-staged): kxT (bf16, [hb][d][t]) + ks
  mfma_gemm<0><<<dim3(8, 64), dim3(256), 0, stream>>>(
      nullptr, k, WkT, bk, w, kxT, nullptr, ks, MB * SEQ, DIN, DIN);
  // fused score generation + write + PV
  pv_fused<<<dim3(8, HBN), dim3(256), 0, stream>>>(kxT, ks, qs, score_ptr, att);
  // out = gather(att) @ Wp + bp
  mfma_gemm<2><<<dim3(8, 64), dim3(256), 0, stream>>>(
      att, nullptr, WpT, bp, nullptr, nullptr, out_ptr, nullptr, MB * SEQ, DIN,
      DIN);
}